// Round 1
// baseline (400.775 us; speedup 1.0000x reference)
//
#include <hip/hip_runtime.h>
#include <math.h>

typedef __attribute__((ext_vector_type(8))) __bf16 bf16x8;
typedef __attribute__((ext_vector_type(4))) float f32x4;
typedef __attribute__((ext_vector_type(4))) unsigned short us4;
typedef unsigned short u16;

#define DEVI static __device__ __forceinline__

// round-to-nearest-even fp32 -> bf16
DEVI u16 f2bf(float f) {
  union { float f; unsigned u; } v; v.f = f;
  unsigned r = v.u + 0x7fffu + ((v.u >> 16) & 1u);
  return (u16)(r >> 16);
}

DEVI void async16(const void* g, void* l) {
  __builtin_amdgcn_global_load_lds((const __attribute__((address_space(1))) void*)g,
                                   (__attribute__((address_space(3))) void*)l, 16, 0, 0);
}

// ---------------- cast fp32 -> bf16 ----------------
__global__ __launch_bounds__(256) void cast_bf16(const float* __restrict__ in,
                                                 u16* __restrict__ out, int n) {
  int i = (blockIdx.x * 256 + threadIdx.x) * 4;
  if (i >= n) return;
  float4 v = *(const float4*)(in + i);
  us4 o = { f2bf(v.x), f2bf(v.y), f2bf(v.z), f2bf(v.w) };
  *(us4*)(out + i) = o;
}

// ---------------- GEMM: C[m,n] = sum_k A[m,k]*B[n,k] (+bias) ----------------
// A: [4096][2048] bf16 row-major, B: [2048][2048] bf16 row-major (i.e. W, = B^T form)
// MODE 0: Q  -> rope, store bf16 [B,H,S,HD]
// MODE 1: K  -> rope, store bf16 [B,H,S,HD] with per-row XOR swizzle
// MODE 2: V  -> store bf16 transposed [B,H,HD,S] with per-64-chunk XOR swizzle
// MODE 3: O  -> store fp32 [4096][2048] + bias
template<int MODE>
__global__ __launch_bounds__(256, 2)
void gemm_bt(const u16* __restrict__ A, const u16* __restrict__ B,
             const float* __restrict__ bias,
             const float* __restrict__ cosT, const float* __restrict__ sinT,
             void* __restrict__ outp)
{
  __shared__ __align__(16) u16 As[4096];   // [128][32]
  __shared__ __align__(16) u16 Bs[4096];   // [128][32]
  const int t = threadIdx.x, w = t >> 6, lane = t & 63;
  const int lrow = lane & 15, lk8 = (lane >> 4) * 8;
  const int brow = blockIdx.y * 128, bcol = blockIdx.x * 128;
  const int wr = (w >> 1) * 64, wc = (w & 1) * 64;

  f32x4 acc[4][4] = {};

  for (int k0 = 0; k0 < 2048; k0 += 32) {
#pragma unroll
    for (int r = 0; r < 2; ++r) {
      int e = (r * 256 + t) * 8;          // element offset in the 128x32 tile
      async16(A + (size_t)(brow + (e >> 5)) * 2048 + k0 + (e & 31), As + r * 2048 + w * 512);
      async16(B + (size_t)(bcol + (e >> 5)) * 2048 + k0 + (e & 31), Bs + r * 2048 + w * 512);
    }
    __syncthreads();
    bf16x8 a[4], b[4];
#pragma unroll
    for (int m = 0; m < 4; ++m) a[m] = *(const bf16x8*)(As + (wr + m * 16 + lrow) * 32 + lk8);
#pragma unroll
    for (int n = 0; n < 4; ++n) b[n] = *(const bf16x8*)(Bs + (wc + n * 16 + lrow) * 32 + lk8);
#pragma unroll
    for (int m = 0; m < 4; ++m)
#pragma unroll
      for (int n = 0; n < 4; ++n)
        acc[m][n] = __builtin_amdgcn_mfma_f32_16x16x32_bf16(a[m], b[n], acc[m][n], 0, 0, 0);
    __syncthreads();
  }

  // epilogue: C/D layout col = lane&15, row = (lane>>4)*4 + r
#pragma unroll
  for (int mi = 0; mi < 4; ++mi) {
#pragma unroll
    for (int ni = 0; ni < 4; ++ni) {
      f32x4 v = acc[mi][ni];
      const int row0 = brow + wr + mi * 16 + (lane >> 4) * 4;
      const int col = bcol + wc + ni * 16 + lrow;
      if constexpr (MODE == 3) {
        float* O = (float*)outp;
        const float bv = bias[col];
#pragma unroll
        for (int r = 0; r < 4; ++r)
          O[(size_t)(row0 + r) * 2048 + col] = v[r] + bv;
      } else if constexpr (MODE == 0 || MODE == 1) {
        u16* O = (u16*)outp;
        const float bv = bias[col];
        const int h = col >> 7, d = col & 127;
        const float sgn = (d & 1) ? 1.f : -1.f;
#pragma unroll
        for (int r = 0; r < 4; ++r) {
          const int row = row0 + r, bb = row >> 11, s = row & 2047;
          float q = v[r] + bv;
          float p = __shfl_xor(q, 1);   // partner dim d^1 lives in lane^1
          float o = q * cosT[s * 128 + d] + sgn * p * sinT[s * 128 + d];
          u16* base = O + ((size_t)(bb * 16 + h) * 2048 + s) * 128;
          if constexpr (MODE == 0) {
            base[d] = f2bf(o);
          } else {
            *(u16*)((char*)base + (((unsigned)(d << 1)) ^ (unsigned)((s & 7) << 4))) = f2bf(o);
          }
        }
      } else { // MODE 2: V -> Vt [B,H,HD,S], 4 consecutive s per lane -> 8B store
        u16* O = (u16*)outp;
        const float bv = bias[col];
        const int h = col >> 7, d = col & 127;
        const int bb = row0 >> 11, s = row0 & 2047;
        us4 ov;
#pragma unroll
        for (int r = 0; r < 4; ++r) ov[r] = f2bf(v[r] + bv);
        u16* base = O + ((size_t)(bb * 16 + h) * 128 + d) * 2048 + (s & ~63);
        *(us4*)((char*)base + ((unsigned)((s & 63) << 1) ^ (unsigned)((d & 7) << 4))) = ov;
      }
    }
  }
}

// ---------------- causal flash attention ----------------
// Q: [BH][S][128] bf16 (plain), K: [BH][S][128] bf16 (row-swizzled),
// Vt: [BH][128][S] bf16 (chunk-swizzled). AO out: [4096][2048] bf16.
__global__ __launch_bounds__(256, 2)
void attn_fwd(const u16* __restrict__ Q, const u16* __restrict__ K,
              const u16* __restrict__ Vt, u16* __restrict__ AO)
{
  __shared__ __align__(16) u16 Ks[64 * 128];
  __shared__ __align__(16) u16 Vs[128 * 64];
  __shared__ __align__(16) u16 Ps[4][16 * 72];   // per-wave P, +8 pad for banks
  const int t = threadIdx.x, w = t >> 6, lane = t & 63;
  const int lrow = lane & 15, lk8 = (lane >> 4) * 8;
  const int bh = blockIdx.y, qb = blockIdx.x;
  const int q0 = qb * 64, qw = q0 + w * 16;
  const u16* Qg = Q + (size_t)bh * 2048 * 128;
  const u16* Kg = K + (size_t)bh * 2048 * 128;
  const u16* Vg = Vt + (size_t)bh * 128 * 2048;

  // Q fragments in registers (A-operand: row=lane&15 -> q, k=d chunks)
  bf16x8 qf[4];
#pragma unroll
  for (int c = 0; c < 4; ++c)
    qf[c] = *(const bf16x8*)(Qg + (size_t)(qw + lrow) * 128 + lk8 + c * 32);

  f32x4 acc_o[8] = {};
  float mrow[4], lsum[4];
#pragma unroll
  for (int r = 0; r < 4; ++r) { mrow[r] = -1e30f; lsum[r] = 0.f; }

  const float scale = 0.08838834764831845f;  // 1/sqrt(128)
  const int nkv = qb + 1;
  for (int i = 0; i < nkv; ++i) {
    // stage K tile [64][128] and Vt tile [128][64] (both contiguous-chunk copies)
#pragma unroll
    for (int r = 0; r < 4; ++r) {
      int e = (r * 256 + t) * 8;
      async16(Kg + (size_t)i * 8192 + e, Ks + r * 2048 + w * 512);
      async16(Vg + (size_t)(e >> 6) * 2048 + i * 64 + (e & 63), Vs + r * 2048 + w * 512);
    }
    __syncthreads();

    // QK^T: scores [16 q][64 k] per wave
    f32x4 sc[4];
#pragma unroll
    for (int kt = 0; kt < 4; ++kt) {
      f32x4 s = {};
      const int krow = kt * 16 + lrow;
      const char* kbase = (const char*)(Ks + krow * 128);
      const unsigned sw = (unsigned)((krow & 7) << 4);
#pragma unroll
      for (int c = 0; c < 4; ++c) {
        bf16x8 kf = *(const bf16x8*)(kbase + ((unsigned)((lk8 + c * 32) << 1) ^ sw));
        s = __builtin_amdgcn_mfma_f32_16x16x32_bf16(qf[c], kf, s, 0, 0, 0);
      }
      sc[kt] = s;
    }

    // scale + causal mask (only diagonal block needs it)
    const bool lastblk = (i == qb);
    float pv[4][4];
#pragma unroll
    for (int kt = 0; kt < 4; ++kt)
#pragma unroll
      for (int r = 0; r < 4; ++r) {
        float sv = sc[kt][r] * scale;
        if (lastblk) {
          int kg = i * 64 + kt * 16 + lrow;
          int qg = qw + (lane >> 4) * 4 + r;
          if (kg > qg) sv = -1e30f;
        }
        pv[kt][r] = sv;
      }

    // online softmax (row = fixed per (lane>>4, r); reduce over 16 col-lanes)
    float mc[4], corr[4], rs[4];
#pragma unroll
    for (int r = 0; r < 4; ++r) {
      float mm = fmaxf(fmaxf(pv[0][r], pv[1][r]), fmaxf(pv[2][r], pv[3][r]));
#pragma unroll
      for (int d = 1; d < 16; d <<= 1) mm = fmaxf(mm, __shfl_xor(mm, d));
      float mn = fmaxf(mrow[r], mm);
      corr[r] = __expf(mrow[r] - mn);
      mrow[r] = mn;
      rs[r] = 0.f;
    }
#pragma unroll
    for (int kt = 0; kt < 4; ++kt)
#pragma unroll
      for (int r = 0; r < 4; ++r) {
        float p = __expf(pv[kt][r] - mrow[r]);
        pv[kt][r] = p;
        rs[r] += p;
      }
#pragma unroll
    for (int r = 0; r < 4; ++r) {
#pragma unroll
      for (int d = 1; d < 16; d <<= 1) rs[r] += __shfl_xor(rs[r], d);
      lsum[r] = lsum[r] * corr[r] + rs[r];
    }
#pragma unroll
    for (int nt = 0; nt < 8; ++nt)
#pragma unroll
      for (int r = 0; r < 4; ++r) acc_o[nt][r] *= corr[r];

    // P -> LDS (C layout) -> A-frag layout
    u16* Pw = &Ps[w][0];
#pragma unroll
    for (int kt = 0; kt < 4; ++kt)
#pragma unroll
      for (int r = 0; r < 4; ++r)
        Pw[((lane >> 4) * 4 + r) * 72 + kt * 16 + lrow] = f2bf(pv[kt][r]);
    bf16x8 pf[2];
#pragma unroll
    for (int kc = 0; kc < 2; ++kc)
      pf[kc] = *(const bf16x8*)(Pw + lrow * 72 + lk8 + kc * 32);

    // PV: acc_o[nt] += P[16q x 64k] * V[64k x 128d]
#pragma unroll
    for (int nt = 0; nt < 8; ++nt) {
      const int vrow = nt * 16 + lrow;
      const char* vbase = (const char*)(Vs + vrow * 64);
      const unsigned sw2 = (unsigned)((vrow & 7) << 4);
#pragma unroll
      for (int kc = 0; kc < 2; ++kc) {
        bf16x8 vf = *(const bf16x8*)(vbase + ((unsigned)((lk8 + kc * 32) << 1) ^ sw2));
        acc_o[nt] = __builtin_amdgcn_mfma_f32_16x16x32_bf16(pf[kc], vf, acc_o[nt], 0, 0, 0);
      }
    }
    __syncthreads();
  }

  // epilogue: AO[b*S+s][h*128+d] = O/l
  const int bb = bh >> 4, h = bh & 15;
#pragma unroll
  for (int nt = 0; nt < 8; ++nt) {
    const int dcol = nt * 16 + lrow;
#pragma unroll
    for (int r = 0; r < 4; ++r) {
      const int qg = qw + (lane >> 4) * 4 + r;
      float o = acc_o[nt][r] / lsum[r];
      AO[((size_t)(bb * 2048 + qg)) * 2048 + h * 128 + dcol] = f2bf(o);
    }
  }
}

// ---------------- launch ----------------
extern "C" void kernel_launch(void* const* d_in, const int* in_sizes, int n_in,
                              void* d_out, int out_size, void* d_ws, size_t ws_size,
                              hipStream_t stream) {
  const float* x    = (const float*)d_in[0];
  const float* cosT = (const float*)d_in[1];
  const float* sinT = (const float*)d_in[2];
  const float* Wq   = (const float*)d_in[4];
  const float* bq   = (const float*)d_in[5];
  const float* Wk   = (const float*)d_in[6];
  const float* bk   = (const float*)d_in[7];
  const float* Wv   = (const float*)d_in[8];
  const float* bv   = (const float*)d_in[9];
  const float* Wo   = (const float*)d_in[10];
  const float* bo   = (const float*)d_in[11];
  float* out = (float*)d_out;

  char* ws = (char*)d_ws;
  u16* xb  = (u16*)(ws);                    // 16 MB  [4096][2048]
  u16* Wqb = (u16*)(ws + (16u << 20));      // 8 MB
  u16* Wkb = (u16*)(ws + (24u << 20));
  u16* Wvb = (u16*)(ws + (32u << 20));
  u16* Wob = (u16*)(ws + (40u << 20));
  u16* Qb  = (u16*)(ws + (48u << 20));      // 16 MB [BH][S][HD]
  u16* Kb  = (u16*)(ws + (64u << 20));      // 16 MB [BH][S][HD] swizzled
  u16* Vtb = (u16*)(ws + (80u << 20));      // 16 MB [BH][HD][S] swizzled
  u16* AOb = (u16*)(ws + (96u << 20));      // 16 MB [4096][2048]

  cast_bf16<<<8192, 256, 0, stream>>>(x,  xb,  4096 * 2048);
  cast_bf16<<<4096, 256, 0, stream>>>(Wq, Wqb, 2048 * 2048);
  cast_bf16<<<4096, 256, 0, stream>>>(Wk, Wkb, 2048 * 2048);
  cast_bf16<<<4096, 256, 0, stream>>>(Wv, Wvb, 2048 * 2048);
  cast_bf16<<<4096, 256, 0, stream>>>(Wo, Wob, 2048 * 2048);

  dim3 gg(16, 32);  // N/128, M/128
  gemm_bt<0><<<gg, 256, 0, stream>>>(xb, Wqb, bq, cosT, sinT, (void*)Qb);
  gemm_bt<1><<<gg, 256, 0, stream>>>(xb, Wkb, bk, cosT, sinT, (void*)Kb);
  gemm_bt<2><<<gg, 256, 0, stream>>>(xb, Wvb, bv, nullptr, nullptr, (void*)Vtb);

  attn_fwd<<<dim3(32, 32), 256, 0, stream>>>(Qb, Kb, Vtb, AOb);

  gemm_bt<3><<<gg, 256, 0, stream>>>(AOb, Wob, bo, nullptr, nullptr, (void*)out);
}

// Round 2
// 309.746 us; speedup vs baseline: 1.2939x; 1.2939x over previous
//
#include <hip/hip_runtime.h>
#include <math.h>

typedef __attribute__((ext_vector_type(8))) __bf16 bf16x8;
typedef __attribute__((ext_vector_type(4))) float f32x4;
typedef __attribute__((ext_vector_type(4))) unsigned short us4;
typedef unsigned short u16;

#define DEVI static __device__ __forceinline__

// round-to-nearest-even fp32 -> bf16
DEVI u16 f2bf(float f) {
  union { float f; unsigned u; } v; v.f = f;
  unsigned r = v.u + 0x7fffu + ((v.u >> 16) & 1u);
  return (u16)(r >> 16);
}

DEVI void async16(const void* g, void* l) {
  __builtin_amdgcn_global_load_lds((const __attribute__((address_space(1))) void*)g,
                                   (__attribute__((address_space(3))) void*)l, 16, 0, 0);
}

// ---------------- cast fp32 -> bf16 ----------------
__global__ __launch_bounds__(256) void cast_bf16(const float* __restrict__ in,
                                                 u16* __restrict__ out, int n) {
  int i = (blockIdx.x * 256 + threadIdx.x) * 4;
  if (i >= n) return;
  float4 v = *(const float4*)(in + i);
  us4 o = { f2bf(v.x), f2bf(v.y), f2bf(v.z), f2bf(v.w) };
  *(us4*)(out + i) = o;
}

// ---------------- GEMM: C[m,n] = sum_k A[m,k]*B[n,k] (+bias) ----------------
template<int MODE>
__global__ __launch_bounds__(256, 2)
void gemm_bt(const u16* __restrict__ A, const u16* __restrict__ B,
             const float* __restrict__ bias,
             const float* __restrict__ cosT, const float* __restrict__ sinT,
             void* __restrict__ outp)
{
  __shared__ __align__(16) u16 As[4096];   // [128][32]
  __shared__ __align__(16) u16 Bs[4096];   // [128][32]
  const int t = threadIdx.x, w = t >> 6, lane = t & 63;
  const int lrow = lane & 15, lk8 = (lane >> 4) * 8;
  const int brow = blockIdx.y * 128, bcol = blockIdx.x * 128;
  const int wr = (w >> 1) * 64, wc = (w & 1) * 64;

  f32x4 acc[4][4] = {};

  for (int k0 = 0; k0 < 2048; k0 += 32) {
#pragma unroll
    for (int r = 0; r < 2; ++r) {
      int e = (r * 256 + t) * 8;          // element offset in the 128x32 tile
      async16(A + (size_t)(brow + (e >> 5)) * 2048 + k0 + (e & 31), As + r * 2048 + w * 512);
      async16(B + (size_t)(bcol + (e >> 5)) * 2048 + k0 + (e & 31), Bs + r * 2048 + w * 512);
    }
    __syncthreads();
    bf16x8 a[4], b[4];
#pragma unroll
    for (int m = 0; m < 4; ++m) a[m] = *(const bf16x8*)(As + (wr + m * 16 + lrow) * 32 + lk8);
#pragma unroll
    for (int n = 0; n < 4; ++n) b[n] = *(const bf16x8*)(Bs + (wc + n * 16 + lrow) * 32 + lk8);
#pragma unroll
    for (int m = 0; m < 4; ++m)
#pragma unroll
      for (int n = 0; n < 4; ++n)
        acc[m][n] = __builtin_amdgcn_mfma_f32_16x16x32_bf16(a[m], b[n], acc[m][n], 0, 0, 0);
    __syncthreads();
  }

  // epilogue: C/D layout col = lane&15, row = (lane>>4)*4 + r
#pragma unroll
  for (int mi = 0; mi < 4; ++mi) {
#pragma unroll
    for (int ni = 0; ni < 4; ++ni) {
      f32x4 v = acc[mi][ni];
      const int row0 = brow + wr + mi * 16 + (lane >> 4) * 4;
      const int col = bcol + wc + ni * 16 + lrow;
      if constexpr (MODE == 3) {
        float* O = (float*)outp;
        const float bv = bias[col];
#pragma unroll
        for (int r = 0; r < 4; ++r)
          O[(size_t)(row0 + r) * 2048 + col] = v[r] + bv;
      } else if constexpr (MODE == 0 || MODE == 1) {
        u16* O = (u16*)outp;
        const float bv = bias[col];
        const int h = col >> 7, d = col & 127;
        const float sgn = (d & 1) ? 1.f : -1.f;
#pragma unroll
        for (int r = 0; r < 4; ++r) {
          const int row = row0 + r, bb = row >> 11, s = row & 2047;
          float q = v[r] + bv;
          float p = __shfl_xor(q, 1);   // partner dim d^1 lives in lane^1
          float o = q * cosT[s * 128 + d] + sgn * p * sinT[s * 128 + d];
          u16* base = O + ((size_t)(bb * 16 + h) * 2048 + s) * 128;
          if constexpr (MODE == 0) {
            base[d] = f2bf(o);
          } else {
            *(u16*)((char*)base + (((unsigned)(d << 1)) ^ (unsigned)((s & 7) << 4))) = f2bf(o);
          }
        }
      } else { // MODE 2: V -> Vt [B,H,HD,S], 4 consecutive s per lane -> 8B store
        u16* O = (u16*)outp;
        const float bv = bias[col];
        const int h = col >> 7, d = col & 127;
        const int bb = row0 >> 11, s = row0 & 2047;
        us4 ov;
#pragma unroll
        for (int r = 0; r < 4; ++r) ov[r] = f2bf(v[r] + bv);
        u16* base = O + ((size_t)(bb * 16 + h) * 128 + d) * 2048 + (s & ~63);
        *(us4*)((char*)base + ((unsigned)((s & 63) << 1) ^ (unsigned)((d & 7) << 4))) = ov;
      }
    }
  }
}

// ---------------- causal flash attention ----------------
// Q: [BH][S][128] bf16 (plain), K: [BH][S][128] bf16 (row-swizzled),
// Vt: [BH][128][S] bf16 (chunk-swizzled). AO out: [4096][2048] bf16.
// Folded pairing: block handles q-tiles {p, 31-p} -> uniform 33 KV-iters.
// Double-buffered K/V staging, counted vmcnt(8), raw barriers.
__global__ __launch_bounds__(256, 2)
void attn_fwd(const u16* __restrict__ Q, const u16* __restrict__ K,
              const u16* __restrict__ Vt, u16* __restrict__ AO)
{
  __shared__ __align__(16) u16 Ks[2][64 * 128];
  __shared__ __align__(16) u16 Vs[2][128 * 64];
  __shared__ __align__(16) u16 Ps[4][16 * 72];   // per-wave P, +8 pad
  const int t = threadIdx.x, w = t >> 6, lane = t & 63;
  const int lrow = lane & 15, lk8 = (lane >> 4) * 8;
  // XCD swizzle: blocks of one bh share an XCD (xcd = id%8 assumed)
  const int id = blockIdx.x;
  const int bh = (id & 7) | (((id >> 3) & 3) << 3);
  const int pr = id >> 5;                         // pair index 0..15
  const u16* Qg = Q + (size_t)bh * 2048 * 128;
  const u16* Kg = K + (size_t)bh * 2048 * 128;
  const u16* Vg = Vt + (size_t)bh * 128 * 2048;
  const int bb = bh >> 4, h = bh & 15;
  const float scale = 0.08838834764831845f;  // 1/sqrt(128)

  for (int half = 0; half < 2; ++half) {
    const int qt = half ? (31 - pr) : pr;
    const int q0 = qt * 64, qw = q0 + w * 16;
    const int nkv = qt + 1;

    // Q fragments in registers (A-operand)
    bf16x8 qf[4];
#pragma unroll
    for (int c = 0; c < 4; ++c)
      qf[c] = *(const bf16x8*)(Qg + (size_t)(qw + lrow) * 128 + lk8 + c * 32);

    f32x4 acc_o[8] = {};
    float mrow[4], lsum[4];
#pragma unroll
    for (int r = 0; r < 4; ++r) { mrow[r] = -1e30f; lsum[r] = 0.f; }

    // stage tile i into buffer b: 8 global_load_lds per wave (4 K + 4 V)
    auto stage = [&](int i, int b) {
#pragma unroll
      for (int r = 0; r < 4; ++r) {
        int e = (r * 256 + t) * 8;
        async16(Kg + (size_t)i * 8192 + e, &Ks[b][r * 2048 + w * 512]);
        async16(Vg + (size_t)(e >> 6) * 2048 + i * 64 + (e & 63), &Vs[b][r * 2048 + w * 512]);
      }
    };

    stage(0, 0);
    for (int i = 0; i < nkv; ++i) {
      const int cur = i & 1;
      const bool pf = (i + 1) < nkv;
      if (pf) stage(i + 1, cur ^ 1);
      if (pf) asm volatile("s_waitcnt vmcnt(8)" ::: "memory");
      else    asm volatile("s_waitcnt vmcnt(0)" ::: "memory");
      __builtin_amdgcn_s_barrier();
      __builtin_amdgcn_sched_barrier(0);

      // QK^T: scores [16 q][64 k] per wave
      f32x4 sc[4];
      __builtin_amdgcn_s_setprio(1);
#pragma unroll
      for (int kt = 0; kt < 4; ++kt) {
        f32x4 s = {};
        const int krow = kt * 16 + lrow;
        const char* kbase = (const char*)(&Ks[cur][krow * 128]);
        const unsigned sw = (unsigned)((krow & 7) << 4);
#pragma unroll
        for (int c = 0; c < 4; ++c) {
          bf16x8 kf = *(const bf16x8*)(kbase + ((unsigned)((lk8 + c * 32) << 1) ^ sw));
          s = __builtin_amdgcn_mfma_f32_16x16x32_bf16(qf[c], kf, s, 0, 0, 0);
        }
        sc[kt] = s;
      }
      __builtin_amdgcn_s_setprio(0);

      // scale + causal mask (only diagonal block)
      const bool lastblk = (i == qt);
      float pv[4][4];
#pragma unroll
      for (int kt = 0; kt < 4; ++kt)
#pragma unroll
        for (int r = 0; r < 4; ++r) {
          float sv = sc[kt][r] * scale;
          if (lastblk) {
            int kg = i * 64 + kt * 16 + lrow;
            int qg = qw + (lane >> 4) * 4 + r;
            if (kg > qg) sv = -1e30f;
          }
          pv[kt][r] = sv;
        }

      // online softmax (row fixed per (lane>>4, r); reduce over 16 col-lanes)
      float corr[4], rs[4];
#pragma unroll
      for (int r = 0; r < 4; ++r) {
        float mm = fmaxf(fmaxf(pv[0][r], pv[1][r]), fmaxf(pv[2][r], pv[3][r]));
#pragma unroll
        for (int d = 1; d < 16; d <<= 1) mm = fmaxf(mm, __shfl_xor(mm, d));
        float mn = fmaxf(mrow[r], mm);
        corr[r] = __expf(mrow[r] - mn);
        mrow[r] = mn;
        rs[r] = 0.f;
      }
#pragma unroll
      for (int kt = 0; kt < 4; ++kt)
#pragma unroll
        for (int r = 0; r < 4; ++r) {
          float p = __expf(pv[kt][r] - mrow[r]);
          pv[kt][r] = p;
          rs[r] += p;
        }
#pragma unroll
      for (int r = 0; r < 4; ++r) {
#pragma unroll
        for (int d = 1; d < 16; d <<= 1) rs[r] += __shfl_xor(rs[r], d);
        lsum[r] = lsum[r] * corr[r] + rs[r];
      }
#pragma unroll
      for (int nt = 0; nt < 8; ++nt)
#pragma unroll
        for (int r = 0; r < 4; ++r) acc_o[nt][r] *= corr[r];

      // P -> LDS (C layout) -> A-frag layout
      u16* Pw = &Ps[w][0];
#pragma unroll
      for (int kt = 0; kt < 4; ++kt)
#pragma unroll
        for (int r = 0; r < 4; ++r)
          Pw[((lane >> 4) * 4 + r) * 72 + kt * 16 + lrow] = f2bf(pv[kt][r]);
      bf16x8 pf2[2];
#pragma unroll
      for (int kc = 0; kc < 2; ++kc)
        pf2[kc] = *(const bf16x8*)(Pw + lrow * 72 + lk8 + kc * 32);

      // PV: acc_o[nt] += P[16q x 64k] * V[64k x 128d]
      __builtin_amdgcn_s_setprio(1);
#pragma unroll
      for (int nt = 0; nt < 8; ++nt) {
        const int vrow = nt * 16 + lrow;
        const char* vbase = (const char*)(&Vs[cur][vrow * 64]);
        const unsigned sw2 = (unsigned)((vrow & 7) << 4);
#pragma unroll
        for (int kc = 0; kc < 2; ++kc) {
          bf16x8 vf = *(const bf16x8*)(vbase + ((unsigned)((lk8 + kc * 32) << 1) ^ sw2));
          acc_o[nt] = __builtin_amdgcn_mfma_f32_16x16x32_bf16(pf2[kc], vf, acc_o[nt], 0, 0, 0);
        }
      }
      __builtin_amdgcn_s_setprio(0);
      __builtin_amdgcn_s_barrier();
    }

    // epilogue: AO[b*S+s][h*128+d] = O/l
#pragma unroll
    for (int nt = 0; nt < 8; ++nt) {
      const int dcol = nt * 16 + lrow;
#pragma unroll
      for (int r = 0; r < 4; ++r) {
        const int qg = qw + (lane >> 4) * 4 + r;
        float o = acc_o[nt][r] / lsum[r];
        AO[((size_t)(bb * 2048 + qg)) * 2048 + h * 128 + dcol] = f2bf(o);
      }
    }
  }
}

// ---------------- launch ----------------
extern "C" void kernel_launch(void* const* d_in, const int* in_sizes, int n_in,
                              void* d_out, int out_size, void* d_ws, size_t ws_size,
                              hipStream_t stream) {
  const float* x    = (const float*)d_in[0];
  const float* cosT = (const float*)d_in[1];
  const float* sinT = (const float*)d_in[2];
  const float* Wq   = (const float*)d_in[4];
  const float* bq   = (const float*)d_in[5];
  const float* Wk   = (const float*)d_in[6];
  const float* bk   = (const float*)d_in[7];
  const float* Wv   = (const float*)d_in[8];
  const float* bv   = (const float*)d_in[9];
  const float* Wo   = (const float*)d_in[10];
  const float* bo   = (const float*)d_in[11];
  float* out = (float*)d_out;

  char* ws = (char*)d_ws;
  u16* xb  = (u16*)(ws);                    // 16 MB  [4096][2048]
  u16* Wqb = (u16*)(ws + (16u << 20));      // 8 MB
  u16* Wkb = (u16*)(ws + (24u << 20));
  u16* Wvb = (u16*)(ws + (32u << 20));
  u16* Wob = (u16*)(ws + (40u << 20));
  u16* Qb  = (u16*)(ws + (48u << 20));      // 16 MB [BH][S][HD]
  u16* Kb  = (u16*)(ws + (64u << 20));      // 16 MB [BH][S][HD] swizzled
  u16* Vtb = (u16*)(ws + (80u << 20));      // 16 MB [BH][HD][S] swizzled
  u16* AOb = (u16*)(ws + (96u << 20));      // 16 MB [4096][2048]

  cast_bf16<<<8192, 256, 0, stream>>>(x,  xb,  4096 * 2048);
  cast_bf16<<<4096, 256, 0, stream>>>(Wq, Wqb, 2048 * 2048);
  cast_bf16<<<4096, 256, 0, stream>>>(Wk, Wkb, 2048 * 2048);
  cast_bf16<<<4096, 256, 0, stream>>>(Wv, Wvb, 2048 * 2048);
  cast_bf16<<<4096, 256, 0, stream>>>(Wo, Wob, 2048 * 2048);

  dim3 gg(16, 32);  // N/128, M/128
  gemm_bt<0><<<gg, 256, 0, stream>>>(xb, Wqb, bq, cosT, sinT, (void*)Qb);
  gemm_bt<1><<<gg, 256, 0, stream>>>(xb, Wkb, bk, cosT, sinT, (void*)Kb);
  gemm_bt<2><<<gg, 256, 0, stream>>>(xb, Wvb, bv, nullptr, nullptr, (void*)Vtb);

  attn_fwd<<<512, 256, 0, stream>>>(Qb, Kb, Vtb, AOb);

  gemm_bt<3><<<gg, 256, 0, stream>>>(AOb, Wob, bo, nullptr, nullptr, (void*)out);
}

// Round 3
// 288.986 us; speedup vs baseline: 1.3868x; 1.0718x over previous
//
#include <hip/hip_runtime.h>
#include <math.h>

typedef __attribute__((ext_vector_type(8))) __bf16 bf16x8;
typedef __attribute__((ext_vector_type(4))) float f32x4;
typedef __attribute__((ext_vector_type(4))) unsigned short us4;
typedef unsigned short u16;
typedef unsigned int u32;

#define DEVI static __device__ __forceinline__

// round-to-nearest-even fp32 -> bf16
DEVI u16 f2bf(float f) {
  union { float f; unsigned u; } v; v.f = f;
  unsigned r = v.u + 0x7fffu + ((v.u >> 16) & 1u);
  return (u16)(r >> 16);
}

DEVI void async16(const void* g, void* l) {
  __builtin_amdgcn_global_load_lds((const __attribute__((address_space(1))) void*)g,
                                   (__attribute__((address_space(3))) void*)l, 16, 0, 0);
}

// pack two f32 -> one u32 of 2 bf16 (RNE)
DEVI u32 pkbf(float lo, float hi) {
  u32 r;
  asm("v_cvt_pk_bf16_f32 %0, %1, %2" : "=v"(r) : "v"(lo), "v"(hi));
  return r;
}

// ---------------- cast fp32 -> bf16 ----------------
__global__ __launch_bounds__(256) void cast_bf16(const float* __restrict__ in,
                                                 u16* __restrict__ out, int n) {
  int i = (blockIdx.x * 256 + threadIdx.x) * 4;
  if (i >= n) return;
  float4 v = *(const float4*)(in + i);
  us4 o = { f2bf(v.x), f2bf(v.y), f2bf(v.z), f2bf(v.w) };
  *(us4*)(out + i) = o;
}

// ---------------- GEMM: C[m,n] = sum_k A[m,k]*B[n,k] (+bias) ----------------
// MODE 0: Q  -> rope * (1/sqrt(128) * log2e), store bf16 [B,H,S,HD]
// MODE 1: K  -> rope, store bf16 [B,H,S,HD] with per-row XOR swizzle
// MODE 2: V  -> store bf16 transposed [B,H,HD,S], pi-permuted cols + XOR swizzle
// MODE 3: O  -> store fp32 [4096][2048] + bias
template<int MODE>
__global__ __launch_bounds__(256, 2)
void gemm_bt(const u16* __restrict__ A, const u16* __restrict__ B,
             const float* __restrict__ bias,
             const float* __restrict__ cosT, const float* __restrict__ sinT,
             void* __restrict__ outp)
{
  __shared__ __align__(16) u16 As[4096];   // [128][32]
  __shared__ __align__(16) u16 Bs[4096];   // [128][32]
  const int t = threadIdx.x, w = t >> 6, lane = t & 63;
  const int lrow = lane & 15, lk8 = (lane >> 4) * 8;
  const int brow = blockIdx.y * 128, bcol = blockIdx.x * 128;
  const int wr = (w >> 1) * 64, wc = (w & 1) * 64;

  f32x4 acc[4][4] = {};

  for (int k0 = 0; k0 < 2048; k0 += 32) {
#pragma unroll
    for (int r = 0; r < 2; ++r) {
      int e = (r * 256 + t) * 8;          // element offset in the 128x32 tile
      async16(A + (size_t)(brow + (e >> 5)) * 2048 + k0 + (e & 31), As + r * 2048 + w * 512);
      async16(B + (size_t)(bcol + (e >> 5)) * 2048 + k0 + (e & 31), Bs + r * 2048 + w * 512);
    }
    __syncthreads();
    bf16x8 a[4], b[4];
#pragma unroll
    for (int m = 0; m < 4; ++m) a[m] = *(const bf16x8*)(As + (wr + m * 16 + lrow) * 32 + lk8);
#pragma unroll
    for (int n = 0; n < 4; ++n) b[n] = *(const bf16x8*)(Bs + (wc + n * 16 + lrow) * 32 + lk8);
#pragma unroll
    for (int m = 0; m < 4; ++m)
#pragma unroll
      for (int n = 0; n < 4; ++n)
        acc[m][n] = __builtin_amdgcn_mfma_f32_16x16x32_bf16(a[m], b[n], acc[m][n], 0, 0, 0);
    __syncthreads();
  }

  // epilogue: C/D layout col = lane&15, row = (lane>>4)*4 + r
#pragma unroll
  for (int mi = 0; mi < 4; ++mi) {
#pragma unroll
    for (int ni = 0; ni < 4; ++ni) {
      f32x4 v = acc[mi][ni];
      const int row0 = brow + wr + mi * 16 + (lane >> 4) * 4;
      const int col = bcol + wc + ni * 16 + lrow;
      if constexpr (MODE == 3) {
        float* O = (float*)outp;
        const float bv = bias[col];
#pragma unroll
        for (int r = 0; r < 4; ++r)
          O[(size_t)(row0 + r) * 2048 + col] = v[r] + bv;
      } else if constexpr (MODE == 0 || MODE == 1) {
        u16* O = (u16*)outp;
        const float bv = bias[col];
        const int h = col >> 7, d = col & 127;
        const float sgn = (d & 1) ? 1.f : -1.f;
        const float QSCL = 0.08838834764831845f * 1.44269504088896340f;
#pragma unroll
        for (int r = 0; r < 4; ++r) {
          const int row = row0 + r, bb = row >> 11, s = row & 2047;
          float q = v[r] + bv;
          float p = __shfl_xor(q, 1);   // partner dim d^1 lives in lane^1
          float o = q * cosT[s * 128 + d] + sgn * p * sinT[s * 128 + d];
          if constexpr (MODE == 0) o *= QSCL;
          u16* base = O + ((size_t)(bb * 16 + h) * 2048 + s) * 128;
          if constexpr (MODE == 0) {
            base[d] = f2bf(o);
          } else {
            *(u16*)((char*)base + (((unsigned)(d << 1)) ^ (unsigned)((s & 7) << 4))) = f2bf(o);
          }
        }
      } else { // MODE 2: V -> Vt [B,H,HD,S], pi-permuted within each 64-col block
        u16* O = (u16*)outp;
        const float bv = bias[col];
        const int h = col >> 7, d = col & 127;
        const int bb = row0 >> 11, s = row0 & 2047;
        us4 ov;
#pragma unroll
        for (int r = 0; r < 4; ++r) ov[r] = f2bf(v[r] + bv);
        // logical offset l = s&63 -> physical slot c = 32*(kt>>1) + 8*g + 4*(kt&1)
        const int l = s & 63;
        const int kt = l >> 4, g2 = (l >> 2) & 3;
        const int c = ((kt >> 1) << 5) + (g2 << 3) + ((kt & 1) << 2);
        u16* base = O + ((size_t)(bb * 16 + h) * 128 + d) * 2048 + (s & ~63);
        *(us4*)((char*)base + ((unsigned)(c << 1) ^ (unsigned)((d & 7) << 4))) = ov;
      }
    }
  }
}

// ---------------- causal flash attention ----------------
// Q: [BH][S][128] bf16 pre-scaled by 1/sqrt(128)*log2e, K: row-swizzled,
// Vt: [BH][128][S] pi-permuted + swizzled. AO out: [4096][2048] bf16.
// Swapped-operand MFMA: lane owns one q-row (q = lane&15); softmax fully
// lane-local; P -> PV via in-register cvt_pk packing (zero LDS, zero shfl).
__global__ __launch_bounds__(256, 2)
void attn_fwd(const u16* __restrict__ Q, const u16* __restrict__ K,
              const u16* __restrict__ Vt, u16* __restrict__ AO)
{
  __shared__ __align__(16) u16 Ks[2][64 * 128];
  __shared__ __align__(16) u16 Vs[2][128 * 64];
  const int t = threadIdx.x, w = t >> 6, lane = t & 63;
  const int lrow = lane & 15, g = lane >> 4, lk8 = g * 8;
  const int id = blockIdx.x;
  const int bh = (id & 7) | (((id >> 3) & 3) << 3);   // XCD-local bh grouping
  const int pr = id >> 5;                              // pair index 0..15
  const u16* Qg = Q + (size_t)bh * 2048 * 128;
  const u16* Kg = K + (size_t)bh * 2048 * 128;
  const u16* Vg = Vt + (size_t)bh * 128 * 2048;
  const int bb = bh >> 4, h = bh & 15;

  for (int half = 0; half < 2; ++half) {
    const int qt = half ? (31 - pr) : pr;
    const int q0 = qt * 64, qw = q0 + w * 16;
    const int nkv = qt + 1;
    const int qg = qw + lrow;   // this lane's q-row

    // Q fragments (B-operand: lane&15 = q-row)
    bf16x8 qf[4];
#pragma unroll
    for (int c = 0; c < 4; ++c)
      qf[c] = *(const bf16x8*)(Qg + (size_t)(qw + lrow) * 128 + lk8 + c * 32);

    f32x4 acc_o[8] = {};
    float m = -1e30f, lsum = 0.f;

    auto stage = [&](int i, int b) {
#pragma unroll
      for (int r = 0; r < 4; ++r) {
        int e = (r * 256 + t) * 8;
        async16(Kg + (size_t)i * 8192 + e, &Ks[b][r * 2048 + w * 512]);
        async16(Vg + (size_t)(e >> 6) * 2048 + i * 64 + (e & 63), &Vs[b][r * 2048 + w * 512]);
      }
    };

    stage(0, 0);
    for (int i = 0; i < nkv; ++i) {
      const int cur = i & 1;
      const bool pfch = (i + 1) < nkv;
      if (pfch) stage(i + 1, cur ^ 1);
      if (pfch) asm volatile("s_waitcnt vmcnt(8)" ::: "memory");
      else      asm volatile("s_waitcnt vmcnt(0)" ::: "memory");
      __builtin_amdgcn_s_barrier();
      __builtin_amdgcn_sched_barrier(0);

      // QK^T swapped: A = K-rows, B = Q -> C col = q (lane&15), row = k
      f32x4 sc[4];
      __builtin_amdgcn_s_setprio(1);
#pragma unroll
      for (int kt = 0; kt < 4; ++kt) {
        f32x4 s = {};
        const int krow = kt * 16 + lrow;
        const char* kbase = (const char*)(&Ks[cur][krow * 128]);
        const unsigned sw = (unsigned)((krow & 7) << 4);
#pragma unroll
        for (int c = 0; c < 4; ++c) {
          bf16x8 kf = *(const bf16x8*)(kbase + ((unsigned)((lk8 + c * 32) << 1) ^ sw));
          s = __builtin_amdgcn_mfma_f32_16x16x32_bf16(kf, qf[c], s, 0, 0, 0);
        }
        sc[kt] = s;
      }
      __builtin_amdgcn_s_setprio(0);

      // per-lane scores: p[kt][r] = S'[q=qg][k = i*64 + kt*16 + 4g + r] (log2-domain)
      float p[4][4];
      const bool lastblk = (i == qt);
      if (lastblk) {
#pragma unroll
        for (int kt = 0; kt < 4; ++kt)
#pragma unroll
          for (int r = 0; r < 4; ++r) {
            int kg = i * 64 + kt * 16 + g * 4 + r;
            p[kt][r] = (kg > qg) ? -1e30f : sc[kt][r];
          }
      } else {
#pragma unroll
        for (int kt = 0; kt < 4; ++kt)
#pragma unroll
          for (int r = 0; r < 4; ++r) p[kt][r] = sc[kt][r];
      }

      // row max: 15 in-lane + reduce over the 4 lane-groups
      float mm = p[0][0];
#pragma unroll
      for (int kt = 0; kt < 4; ++kt)
#pragma unroll
        for (int r = 0; r < 4; ++r) mm = fmaxf(mm, p[kt][r]);
      mm = fmaxf(mm, __shfl_xor(mm, 16));
      mm = fmaxf(mm, __shfl_xor(mm, 32));

      float rs = 0.f;
      if (__any(mm > m + 8.f)) {          // full rescale path
        const float mn = fmaxf(m, mm);
        const float corr = exp2f(m - mn);
        m = mn;
#pragma unroll
        for (int kt = 0; kt < 4; ++kt)
#pragma unroll
          for (int r = 0; r < 4; ++r) { p[kt][r] = exp2f(p[kt][r] - m); rs += p[kt][r]; }
        rs += __shfl_xor(rs, 16);
        rs += __shfl_xor(rs, 32);
        lsum = lsum * corr + rs;
#pragma unroll
        for (int nt = 0; nt < 8; ++nt)
#pragma unroll
          for (int r = 0; r < 4; ++r) acc_o[nt][r] *= corr;
      } else {                            // defer-max: m unchanged, no rescale
#pragma unroll
        for (int kt = 0; kt < 4; ++kt)
#pragma unroll
          for (int r = 0; r < 4; ++r) { p[kt][r] = exp2f(p[kt][r] - m); rs += p[kt][r]; }
        rs += __shfl_xor(rs, 16);
        rs += __shfl_xor(rs, 32);
        lsum += rs;
      }

      // P -> B-frag: pi-permuted V makes this pure in-lane packing
      bf16x8 pb[2];
#pragma unroll
      for (int kc = 0; kc < 2; ++kc) {
        union { u32 d[4]; bf16x8 v; } u;
        u.d[0] = pkbf(p[2 * kc][0], p[2 * kc][1]);
        u.d[1] = pkbf(p[2 * kc][2], p[2 * kc][3]);
        u.d[2] = pkbf(p[2 * kc + 1][0], p[2 * kc + 1][1]);
        u.d[3] = pkbf(p[2 * kc + 1][2], p[2 * kc + 1][3]);
        pb[kc] = u.v;
      }

      // PV swapped: A = Vt-rows (d), B = P -> C col = q, row = d
      __builtin_amdgcn_s_setprio(1);
#pragma unroll
      for (int nt = 0; nt < 8; ++nt) {
        const int vrow = nt * 16 + lrow;
        const char* vbase = (const char*)(&Vs[cur][vrow * 64]);
        const unsigned sw2 = (unsigned)((vrow & 7) << 4);
#pragma unroll
        for (int kc = 0; kc < 2; ++kc) {
          bf16x8 vf = *(const bf16x8*)(vbase + ((unsigned)((lk8 + kc * 32) << 1) ^ sw2));
          acc_o[nt] = __builtin_amdgcn_mfma_f32_16x16x32_bf16(vf, pb[kc], acc_o[nt], 0, 0, 0);
        }
      }
      __builtin_amdgcn_s_setprio(0);
      __builtin_amdgcn_s_barrier();
    }

    // epilogue: O[q=lrow][d = nt*16 + 4g + r] / lsum
    const float inv_l = 1.f / lsum;
#pragma unroll
    for (int nt = 0; nt < 8; ++nt) {
      us4 ov;
#pragma unroll
      for (int r = 0; r < 4; ++r) ov[r] = f2bf(acc_o[nt][r] * inv_l);
      *(us4*)(AO + ((size_t)(bb * 2048 + qg)) * 2048 + h * 128 + nt * 16 + g * 4) = ov;
    }
  }
}

// ---------------- launch ----------------
extern "C" void kernel_launch(void* const* d_in, const int* in_sizes, int n_in,
                              void* d_out, int out_size, void* d_ws, size_t ws_size,
                              hipStream_t stream) {
  const float* x    = (const float*)d_in[0];
  const float* cosT = (const float*)d_in[1];
  const float* sinT = (const float*)d_in[2];
  const float* Wq   = (const float*)d_in[4];
  const float* bq   = (const float*)d_in[5];
  const float* Wk   = (const float*)d_in[6];
  const float* bk   = (const float*)d_in[7];
  const float* Wv   = (const float*)d_in[8];
  const float* bv   = (const float*)d_in[9];
  const float* Wo   = (const float*)d_in[10];
  const float* bo   = (const float*)d_in[11];
  float* out = (float*)d_out;

  char* ws = (char*)d_ws;
  u16* xb  = (u16*)(ws);                    // 16 MB  [4096][2048]
  u16* Wqb = (u16*)(ws + (16u << 20));      // 8 MB
  u16* Wkb = (u16*)(ws + (24u << 20));
  u16* Wvb = (u16*)(ws + (32u << 20));
  u16* Wob = (u16*)(ws + (40u << 20));
  u16* Qb  = (u16*)(ws + (48u << 20));      // 16 MB [BH][S][HD] (pre-scaled)
  u16* Kb  = (u16*)(ws + (64u << 20));      // 16 MB [BH][S][HD] swizzled
  u16* Vtb = (u16*)(ws + (80u << 20));      // 16 MB [BH][HD][S] permuted+swizzled
  u16* AOb = (u16*)(ws + (96u << 20));      // 16 MB [4096][2048]

  cast_bf16<<<8192, 256, 0, stream>>>(x,  xb,  4096 * 2048);
  cast_bf16<<<4096, 256, 0, stream>>>(Wq, Wqb, 2048 * 2048);
  cast_bf16<<<4096, 256, 0, stream>>>(Wk, Wkb, 2048 * 2048);
  cast_bf16<<<4096, 256, 0, stream>>>(Wv, Wvb, 2048 * 2048);
  cast_bf16<<<4096, 256, 0, stream>>>(Wo, Wob, 2048 * 2048);

  dim3 gg(16, 32);  // N/128, M/128
  gemm_bt<0><<<gg, 256, 0, stream>>>(xb, Wqb, bq, cosT, sinT, (void*)Qb);
  gemm_bt<1><<<gg, 256, 0, stream>>>(xb, Wkb, bk, cosT, sinT, (void*)Kb);
  gemm_bt<2><<<gg, 256, 0, stream>>>(xb, Wvb, bv, nullptr, nullptr, (void*)Vtb);

  attn_fwd<<<512, 256, 0, stream>>>(Qb, Kb, Vtb, AOb);

  gemm_bt<3><<<gg, 256, 0, stream>>>(AOb, Wob, bo, nullptr, nullptr, (void*)out);
}

// Round 4
// 274.659 us; speedup vs baseline: 1.4592x; 1.0522x over previous
//
#include <hip/hip_runtime.h>
#include <math.h>

typedef __attribute__((ext_vector_type(8))) __bf16 bf16x8;
typedef __attribute__((ext_vector_type(4))) float f32x4;
typedef __attribute__((ext_vector_type(4))) unsigned short us4;
typedef unsigned short u16;
typedef unsigned int u32;

#define DEVI static __device__ __forceinline__

// round-to-nearest-even fp32 -> bf16
DEVI u16 f2bf(float f) {
  union { float f; unsigned u; } v; v.f = f;
  unsigned r = v.u + 0x7fffu + ((v.u >> 16) & 1u);
  return (u16)(r >> 16);
}

DEVI void async16(const void* g, void* l) {
  __builtin_amdgcn_global_load_lds((const __attribute__((address_space(1))) void*)g,
                                   (__attribute__((address_space(3))) void*)l, 16, 0, 0);
}

// pack two f32 -> one u32 of 2 bf16 (RNE)
DEVI u32 pkbf(float lo, float hi) {
  u32 r;
  asm("v_cvt_pk_bf16_f32 %0, %1, %2" : "=v"(r) : "v"(lo), "v"(hi));
  return r;
}

// ---------------- cast fp32 -> bf16 ----------------
__global__ __launch_bounds__(256) void cast_bf16(const float* __restrict__ in,
                                                 u16* __restrict__ out, int n) {
  int i = (blockIdx.x * 256 + threadIdx.x) * 4;
  if (i >= n) return;
  float4 v = *(const float4*)(in + i);
  us4 o = { f2bf(v.x), f2bf(v.y), f2bf(v.z), f2bf(v.w) };
  *(us4*)(out + i) = o;
}

// ---------------- 8-phase GEMM: BM=256, BN=128, BK=64, 8 waves (4Mx2N) ------
// C[m,n] = sum_k A[m,k] * W[n,k]  (+bias, fused epilogues)
// qkv=1: N=6144 over 3 weight slabs (Q rope+scale / K rope+swz / V transp+perm)
// qkv=0: W0 only, fp32 out + bias.
// LDS: 3 buffers x (A 32KB + B 16KB) = 144KB, XOR-swizzled (row&7)<<4;
// write side via inverse-swizzled GLOBAL source, LDS dest linear (G21).
__global__ __launch_bounds__(512, 2)
void gemm8p(const u16* __restrict__ A,
            const u16* __restrict__ W0, const u16* __restrict__ W1, const u16* __restrict__ W2,
            const float* __restrict__ biasQ, const float* __restrict__ biasK,
            const float* __restrict__ biasV,
            const float* __restrict__ cosT, const float* __restrict__ sinT,
            void* __restrict__ out0, void* __restrict__ out1, void* __restrict__ out2,
            int ntn, int qkv)
{
  __shared__ __align__(16) char lds[3 * 49152];
  const int t = threadIdx.x, w = t >> 6, lane = t & 63;
  const int lrow = lane & 15, g = lane >> 4, lk8 = g * 8;
  const int nt = blockIdx.x % ntn, mt = blockIdx.x / ntn;
  const int slab = qkv ? (nt >> 4) : 3;
  const u16* Bp = (slab == 1) ? W1 : (slab == 2) ? W2 : W0;
  const int brow = mt * 256;
  const int bcol = (qkv ? (nt & 15) : nt) * 128;   // row offset within W slab
  const int wm = w >> 1, wn = w & 1;

  // staging: thread t stages 6x16B per K-tile; chunk j -> LDS linear byte
  // j*8192 + t*16; global source pre-inverse-swizzled so read-side XOR works.
  size_t soff[6];
#pragma unroll
  for (int j = 0; j < 6; ++j) {
    int p = j * 8192 + t * 16;              // physical byte in buffer
    int pr = (j < 4) ? p : (p - 32768);     // region-relative
    int r = pr >> 7;                        // row (swizzle keeps row bits)
    int c = ((pr ^ ((r & 7) << 4)) & 127) >> 1;  // logical col (elems)
    soff[j] = (j < 4) ? ((size_t)(brow + r) * 2048 + c)
                      : ((size_t)(bcol + r) * 2048 + c);
  }
  auto stage = [&](int tile, int j, char* buf) {
    const u16* src = (j < 4) ? A : Bp;
    async16(src + soff[j] + tile * 64, buf + j * 8192 + t * 16);
  };

  // fragment read offsets (physical, swizzled)
  int offA[4][2], offB[4][2];
#pragma unroll
  for (int m = 0; m < 4; ++m)
#pragma unroll
    for (int kk = 0; kk < 2; ++kk) {
      const int c = (lk8 + kk * 32) * 2;
      const int ra = wm * 64 + m * 16 + lrow;
      offA[m][kk] = (ra * 128 + c) ^ ((ra & 7) << 4);
      const int rb = wn * 64 + m * 16 + lrow;
      offB[m][kk] = 32768 + ((rb * 128 + c) ^ ((rb & 7) << 4));
    }

  f32x4 acc[4][4] = {};

  // prologue: stage tiles 0,1 -> bufs 0,1; publish tile 0
#pragma unroll
  for (int j = 0; j < 6; ++j) stage(0, j, lds);
#pragma unroll
  for (int j = 0; j < 6; ++j) stage(1, j, lds + 49152);
  asm volatile("s_waitcnt vmcnt(6)" ::: "memory");
  __builtin_amdgcn_s_barrier();

  for (int tt = 0; tt < 32; ++tt) {
    char* cur = lds + (tt % 3) * 49152;
    char* nxt = lds + ((tt + 2) % 3) * 49152;
    const bool st = (tt + 2) < 32;

    // ---- phase 0: B all + A m{0,1}; stage chunks 0-2; MFMA m{0,1} ----
    bf16x8 bfr[4][2], afr[2][2];
#pragma unroll
    for (int n = 0; n < 4; ++n)
#pragma unroll
      for (int kk = 0; kk < 2; ++kk) bfr[n][kk] = *(const bf16x8*)(cur + offB[n][kk]);
#pragma unroll
    for (int m = 0; m < 2; ++m)
#pragma unroll
      for (int kk = 0; kk < 2; ++kk) afr[m][kk] = *(const bf16x8*)(cur + offA[m][kk]);
    if (st) { stage(tt + 2, 0, nxt); stage(tt + 2, 1, nxt); stage(tt + 2, 2, nxt); }
    __builtin_amdgcn_s_barrier();
    asm volatile("s_waitcnt lgkmcnt(0)" ::: "memory");
    __builtin_amdgcn_sched_barrier(0);
    __builtin_amdgcn_s_setprio(1);
#pragma unroll
    for (int m = 0; m < 2; ++m)
#pragma unroll
      for (int n = 0; n < 4; ++n)
#pragma unroll
        for (int kk = 0; kk < 2; ++kk)
          acc[m][n] = __builtin_amdgcn_mfma_f32_16x16x32_bf16(afr[m][kk], bfr[n][kk], acc[m][n], 0, 0, 0);
    __builtin_amdgcn_s_setprio(0);
    __builtin_amdgcn_s_barrier();

    // ---- phase 1: A m{2,3}; stage chunks 3-5; vmcnt; MFMA m{2,3} ----
#pragma unroll
    for (int m = 0; m < 2; ++m)
#pragma unroll
      for (int kk = 0; kk < 2; ++kk) afr[m][kk] = *(const bf16x8*)(cur + offA[m + 2][kk]);
    if (st) { stage(tt + 2, 3, nxt); stage(tt + 2, 4, nxt); stage(tt + 2, 5, nxt); }
    if (tt < 31) {
      if (st) asm volatile("s_waitcnt vmcnt(6)" ::: "memory");
      else    asm volatile("s_waitcnt vmcnt(0)" ::: "memory");
    }
    __builtin_amdgcn_s_barrier();
    asm volatile("s_waitcnt lgkmcnt(0)" ::: "memory");
    __builtin_amdgcn_sched_barrier(0);
    __builtin_amdgcn_s_setprio(1);
#pragma unroll
    for (int m = 0; m < 2; ++m)
#pragma unroll
      for (int n = 0; n < 4; ++n)
#pragma unroll
        for (int kk = 0; kk < 2; ++kk)
          acc[m + 2][n] = __builtin_amdgcn_mfma_f32_16x16x32_bf16(afr[m][kk], bfr[n][kk], acc[m + 2][n], 0, 0, 0);
    __builtin_amdgcn_s_setprio(0);
    __builtin_amdgcn_s_barrier();
  }

  // ---- epilogue ----
  const int g4 = g * 4;
#pragma unroll
  for (int mi = 0; mi < 4; ++mi) {
#pragma unroll
    for (int ni = 0; ni < 4; ++ni) {
      f32x4 v = acc[mi][ni];
      const int row0 = brow + wm * 64 + mi * 16 + g4;
      const int cols = bcol + wn * 64 + ni * 16 + lrow;   // col within slab / N
      if (slab == 3) {
        float* O = (float*)out0;
        const float bv = biasQ[cols];
#pragma unroll
        for (int r = 0; r < 4; ++r)
          O[(size_t)(row0 + r) * 2048 + cols] = v[r] + bv;
      } else if (slab == 2) {   // V -> Vt [B,H,HD,S], pi-permuted + swizzled
        u16* O = (u16*)out2;
        const float bv = biasV[cols];
        const int h = cols >> 7, d = cols & 127;
        const int bb = row0 >> 11, s = row0 & 2047;
        us4 ov;
#pragma unroll
        for (int r = 0; r < 4; ++r) ov[r] = f2bf(v[r] + bv);
        const int l = s & 63;
        const int kt = l >> 4, g2 = (l >> 2) & 3;
        const int c = ((kt >> 1) << 5) + (g2 << 3) + ((kt & 1) << 2);
        u16* base = O + ((size_t)(bb * 16 + h) * 128 + d) * 2048 + (s & ~63);
        *(us4*)((char*)base + ((unsigned)(c << 1) ^ (unsigned)((d & 7) << 4))) = ov;
      } else {                  // Q (0) / K (1): bias + RoPE
        u16* O = (u16*)(slab ? out1 : out0);
        const float bv = slab ? biasK[cols] : biasQ[cols];
        const int h = cols >> 7, d = cols & 127;
        const float sgn = (d & 1) ? 1.f : -1.f;
        const float QSCL = 0.08838834764831845f * 1.44269504088896340f;
#pragma unroll
        for (int r = 0; r < 4; ++r) {
          const int row = row0 + r, bb = row >> 11, s = row & 2047;
          float q = v[r] + bv;
          float p = __shfl_xor(q, 1);   // partner dim d^1 lives in lane^1
          float o = q * cosT[s * 128 + d] + sgn * p * sinT[s * 128 + d];
          u16* base = O + ((size_t)(bb * 16 + h) * 2048 + s) * 128;
          if (slab == 0) {
            base[d] = f2bf(o * QSCL);
          } else {
            *(u16*)((char*)base + (((unsigned)(d << 1)) ^ (unsigned)((s & 7) << 4))) = f2bf(o);
          }
        }
      }
    }
  }
}

// ---------------- causal flash attention ----------------
// Q: [BH][S][128] bf16 pre-scaled by 1/sqrt(128)*log2e, K: row-swizzled,
// Vt: [BH][128][S] pi-permuted + swizzled. AO out: [4096][2048] bf16.
__global__ __launch_bounds__(256, 2)
void attn_fwd(const u16* __restrict__ Q, const u16* __restrict__ K,
              const u16* __restrict__ Vt, u16* __restrict__ AO)
{
  __shared__ __align__(16) u16 Ks[2][64 * 128];
  __shared__ __align__(16) u16 Vs[2][128 * 64];
  const int t = threadIdx.x, w = t >> 6, lane = t & 63;
  const int lrow = lane & 15, g = lane >> 4, lk8 = g * 8;
  const int id = blockIdx.x;
  const int bh = (id & 7) | (((id >> 3) & 3) << 3);   // XCD-local bh grouping
  const int pr = id >> 5;                              // pair index 0..15
  const u16* Qg = Q + (size_t)bh * 2048 * 128;
  const u16* Kg = K + (size_t)bh * 2048 * 128;
  const u16* Vg = Vt + (size_t)bh * 128 * 2048;
  const int bb = bh >> 4, h = bh & 15;

  for (int half = 0; half < 2; ++half) {
    const int qt = half ? (31 - pr) : pr;
    const int q0 = qt * 64, qw = q0 + w * 16;
    const int nkv = qt + 1;
    const int qg = qw + lrow;   // this lane's q-row

    bf16x8 qf[4];
#pragma unroll
    for (int c = 0; c < 4; ++c)
      qf[c] = *(const bf16x8*)(Qg + (size_t)(qw + lrow) * 128 + lk8 + c * 32);

    f32x4 acc_o[8] = {};
    float m = -1e30f, lsum = 0.f;

    auto stage = [&](int i, int b) {
#pragma unroll
      for (int r = 0; r < 4; ++r) {
        int e = (r * 256 + t) * 8;
        async16(Kg + (size_t)i * 8192 + e, &Ks[b][r * 2048 + w * 512]);
        async16(Vg + (size_t)(e >> 6) * 2048 + i * 64 + (e & 63), &Vs[b][r * 2048 + w * 512]);
      }
    };

    stage(0, 0);
    for (int i = 0; i < nkv; ++i) {
      const int cur = i & 1;
      const bool pfch = (i + 1) < nkv;
      if (pfch) stage(i + 1, cur ^ 1);
      if (pfch) asm volatile("s_waitcnt vmcnt(8)" ::: "memory");
      else      asm volatile("s_waitcnt vmcnt(0)" ::: "memory");
      __builtin_amdgcn_s_barrier();
      __builtin_amdgcn_sched_barrier(0);

      // QK^T swapped: C col = q (lane&15), row = k
      f32x4 sc[4];
      __builtin_amdgcn_s_setprio(1);
#pragma unroll
      for (int kt = 0; kt < 4; ++kt) {
        f32x4 s = {};
        const int krow = kt * 16 + lrow;
        const char* kbase = (const char*)(&Ks[cur][krow * 128]);
        const unsigned sw = (unsigned)((krow & 7) << 4);
#pragma unroll
        for (int c = 0; c < 4; ++c) {
          bf16x8 kf = *(const bf16x8*)(kbase + ((unsigned)((lk8 + c * 32) << 1) ^ sw));
          s = __builtin_amdgcn_mfma_f32_16x16x32_bf16(kf, qf[c], s, 0, 0, 0);
        }
        sc[kt] = s;
      }
      __builtin_amdgcn_s_setprio(0);

      float p[4][4];
      const bool lastblk = (i == qt);
      if (lastblk) {
#pragma unroll
        for (int kt = 0; kt < 4; ++kt)
#pragma unroll
          for (int r = 0; r < 4; ++r) {
            int kg = i * 64 + kt * 16 + g * 4 + r;
            p[kt][r] = (kg > qg) ? -1e30f : sc[kt][r];
          }
      } else {
#pragma unroll
        for (int kt = 0; kt < 4; ++kt)
#pragma unroll
          for (int r = 0; r < 4; ++r) p[kt][r] = sc[kt][r];
      }

      float mm = p[0][0];
#pragma unroll
      for (int kt = 0; kt < 4; ++kt)
#pragma unroll
        for (int r = 0; r < 4; ++r) mm = fmaxf(mm, p[kt][r]);
      mm = fmaxf(mm, __shfl_xor(mm, 16));
      mm = fmaxf(mm, __shfl_xor(mm, 32));

      float rs = 0.f;
      if (__any(mm > m + 8.f)) {
        const float mn = fmaxf(m, mm);
        const float corr = exp2f(m - mn);
        m = mn;
#pragma unroll
        for (int kt = 0; kt < 4; ++kt)
#pragma unroll
          for (int r = 0; r < 4; ++r) { p[kt][r] = exp2f(p[kt][r] - m); rs += p[kt][r]; }
        rs += __shfl_xor(rs, 16);
        rs += __shfl_xor(rs, 32);
        lsum = lsum * corr + rs;
#pragma unroll
        for (int nt = 0; nt < 8; ++nt)
#pragma unroll
          for (int r = 0; r < 4; ++r) acc_o[nt][r] *= corr;
      } else {
#pragma unroll
        for (int kt = 0; kt < 4; ++kt)
#pragma unroll
          for (int r = 0; r < 4; ++r) { p[kt][r] = exp2f(p[kt][r] - m); rs += p[kt][r]; }
        rs += __shfl_xor(rs, 16);
        rs += __shfl_xor(rs, 32);
        lsum += rs;
      }

      bf16x8 pb[2];
#pragma unroll
      for (int kc = 0; kc < 2; ++kc) {
        union { u32 d[4]; bf16x8 v; } u;
        u.d[0] = pkbf(p[2 * kc][0], p[2 * kc][1]);
        u.d[1] = pkbf(p[2 * kc][2], p[2 * kc][3]);
        u.d[2] = pkbf(p[2 * kc + 1][0], p[2 * kc + 1][1]);
        u.d[3] = pkbf(p[2 * kc + 1][2], p[2 * kc + 1][3]);
        pb[kc] = u.v;
      }

      __builtin_amdgcn_s_setprio(1);
#pragma unroll
      for (int nt = 0; nt < 8; ++nt) {
        const int vrow = nt * 16 + lrow;
        const char* vbase = (const char*)(&Vs[cur][vrow * 64]);
        const unsigned sw2 = (unsigned)((vrow & 7) << 4);
#pragma unroll
        for (int kc = 0; kc < 2; ++kc) {
          bf16x8 vf = *(const bf16x8*)(vbase + ((unsigned)((lk8 + kc * 32) << 1) ^ sw2));
          acc_o[nt] = __builtin_amdgcn_mfma_f32_16x16x32_bf16(vf, pb[kc], acc_o[nt], 0, 0, 0);
        }
      }
      __builtin_amdgcn_s_setprio(0);
      __builtin_amdgcn_s_barrier();
    }

    const float inv_l = 1.f / lsum;
#pragma unroll
    for (int nt = 0; nt < 8; ++nt) {
      us4 ov;
#pragma unroll
      for (int r = 0; r < 4; ++r) ov[r] = f2bf(acc_o[nt][r] * inv_l);
      *(us4*)(AO + ((size_t)(bb * 2048 + qg)) * 2048 + h * 128 + nt * 16 + g * 4) = ov;
    }
  }
}

// ---------------- launch ----------------
extern "C" void kernel_launch(void* const* d_in, const int* in_sizes, int n_in,
                              void* d_out, int out_size, void* d_ws, size_t ws_size,
                              hipStream_t stream) {
  const float* x    = (const float*)d_in[0];
  const float* cosT = (const float*)d_in[1];
  const float* sinT = (const float*)d_in[2];
  const float* Wq   = (const float*)d_in[4];
  const float* bq   = (const float*)d_in[5];
  const float* Wk   = (const float*)d_in[6];
  const float* bk   = (const float*)d_in[7];
  const float* Wv   = (const float*)d_in[8];
  const float* bv   = (const float*)d_in[9];
  const float* Wo   = (const float*)d_in[10];
  const float* bo   = (const float*)d_in[11];
  float* out = (float*)d_out;

  char* ws = (char*)d_ws;
  u16* xb  = (u16*)(ws);                    // 16 MB  [4096][2048]
  u16* Wqb = (u16*)(ws + (16u << 20));      // 8 MB
  u16* Wkb = (u16*)(ws + (24u << 20));
  u16* Wvb = (u16*)(ws + (32u << 20));
  u16* Wob = (u16*)(ws + (40u << 20));
  u16* Qb  = (u16*)(ws + (48u << 20));      // 16 MB [BH][S][HD] (pre-scaled)
  u16* Kb  = (u16*)(ws + (64u << 20));      // 16 MB [BH][S][HD] swizzled
  u16* Vtb = (u16*)(ws + (80u << 20));      // 16 MB [BH][HD][S] permuted+swizzled
  u16* AOb = (u16*)(ws + (96u << 20));      // 16 MB [4096][2048]

  cast_bf16<<<8192, 256, 0, stream>>>(x,  xb,  4096 * 2048);
  cast_bf16<<<4096, 256, 0, stream>>>(Wq, Wqb, 2048 * 2048);
  cast_bf16<<<4096, 256, 0, stream>>>(Wk, Wkb, 2048 * 2048);
  cast_bf16<<<4096, 256, 0, stream>>>(Wv, Wvb, 2048 * 2048);
  cast_bf16<<<4096, 256, 0, stream>>>(Wo, Wob, 2048 * 2048);

  // fused QKV: N = 6144, grid = 16 m-tiles x 48 n-tiles = 768 (3 rounds/CU)
  gemm8p<<<768, 512, 0, stream>>>(xb, Wqb, Wkb, Wvb, bq, bk, bv, cosT, sinT,
                                  (void*)Qb, (void*)Kb, (void*)Vtb, 48, 1);

  attn_fwd<<<512, 256, 0, stream>>>(Qb, Kb, Vtb, AOb);

  // output proj: N = 2048, grid = 16 x 16 = 256 (1 block/CU)
  gemm8p<<<256, 512, 0, stream>>>(AOb, Wob, Wob, Wob, bo, bo, bo, nullptr, nullptr,
                                  (void*)out, nullptr, nullptr, 16, 0);
}

// Round 5
// 274.165 us; speedup vs baseline: 1.4618x; 1.0018x over previous
//
#include <hip/hip_runtime.h>
#include <math.h>

typedef __attribute__((ext_vector_type(8))) __bf16 bf16x8;
typedef __attribute__((ext_vector_type(4))) float f32x4;
typedef __attribute__((ext_vector_type(4))) unsigned short us4;
typedef unsigned short u16;
typedef unsigned int u32;

#define DEVI static __device__ __forceinline__

// round-to-nearest-even fp32 -> bf16
DEVI u16 f2bf(float f) {
  union { float f; unsigned u; } v; v.f = f;
  unsigned r = v.u + 0x7fffu + ((v.u >> 16) & 1u);
  return (u16)(r >> 16);
}

DEVI void async16(const void* g, void* l) {
  __builtin_amdgcn_global_load_lds((const __attribute__((address_space(1))) void*)g,
                                   (__attribute__((address_space(3))) void*)l, 16, 0, 0);
}

// pack two f32 -> one u32 of 2 bf16 (RNE)
DEVI u32 pkbf(float lo, float hi) {
  u32 r;
  asm("v_cvt_pk_bf16_f32 %0, %1, %2" : "=v"(r) : "v"(lo), "v"(hi));
  return r;
}

// ---------------- cast fp32 -> bf16 ----------------
__global__ __launch_bounds__(256) void cast_bf16(const float* __restrict__ in,
                                                 u16* __restrict__ out, int n) {
  int i = (blockIdx.x * 256 + threadIdx.x) * 4;
  if (i >= n) return;
  float4 v = *(const float4*)(in + i);
  us4 o = { f2bf(v.x), f2bf(v.y), f2bf(v.z), f2bf(v.w) };
  *(us4*)(out + i) = o;
}

// ---------------- 8-phase GEMM: BM=256, BN=128, BK=64, 8 waves (4Mx2N) ------
// C[m,n] = sum_k A[m,k] * W[n,k]  (+bias, fused epilogues)
// qkv=1: N=6144 over 3 weight slabs (Q rope+scale / K rope+swz / V transp+perm)
// qkv=0: W0 only, fp32 out + bias.
// XCD-stripe decode: xcd = blockIdx&7 owns n-tile stripe [xcd*ntn/8, ...),
// nt fastest within stripe -> per-XCD L2 hot set = stripe's B panels (~3MB)
// + sliding A window, weights HBM-fetched once.
__global__ __launch_bounds__(512, 2)
void gemm8p(const u16* __restrict__ A,
            const u16* __restrict__ W0, const u16* __restrict__ W1, const u16* __restrict__ W2,
            const float* __restrict__ biasQ, const float* __restrict__ biasK,
            const float* __restrict__ biasV,
            const float* __restrict__ cosT, const float* __restrict__ sinT,
            void* __restrict__ out0, void* __restrict__ out1, void* __restrict__ out2,
            int ntn, int qkv)
{
  __shared__ __align__(16) char lds[3 * 49152];
  const int t = threadIdx.x, w = t >> 6, lane = t & 63;
  const int lrow = lane & 15, g = lane >> 4, lk8 = g * 8;
  // XCD-stripe grid decode (ntn % 8 == 0, grid = 16 * ntn)
  const int xcd = blockIdx.x & 7, bi = blockIdx.x >> 3;
  const int ntpx = ntn >> 3;                      // n-tiles per XCD stripe
  const int nt = xcd * ntpx + (bi % ntpx);
  const int mt = bi / ntpx;
  const int slab = qkv ? (nt >> 4) : 3;
  const u16* Bp = (slab == 1) ? W1 : (slab == 2) ? W2 : W0;
  const int brow = mt * 256;
  const int bcol = (qkv ? (nt & 15) : nt) * 128;   // row offset within W slab
  const int wm = w >> 1, wn = w & 1;

  // staging: thread t stages 6x16B per K-tile; chunk j -> LDS linear byte
  // j*8192 + t*16; global source pre-inverse-swizzled so read-side XOR works.
  size_t soff[6];
#pragma unroll
  for (int j = 0; j < 6; ++j) {
    int p = j * 8192 + t * 16;              // physical byte in buffer
    int pr = (j < 4) ? p : (p - 32768);     // region-relative
    int r = pr >> 7;                        // row (swizzle keeps row bits)
    int c = ((pr ^ ((r & 7) << 4)) & 127) >> 1;  // logical col (elems)
    soff[j] = (j < 4) ? ((size_t)(brow + r) * 2048 + c)
                      : ((size_t)(bcol + r) * 2048 + c);
  }
  auto stage = [&](int tile, int j, char* buf) {
    const u16* src = (j < 4) ? A : Bp;
    async16(src + soff[j] + tile * 64, buf + j * 8192 + t * 16);
  };

  // fragment read offsets (physical, swizzled)
  int offA[4][2], offB[4][2];
#pragma unroll
  for (int m = 0; m < 4; ++m)
#pragma unroll
    for (int kk = 0; kk < 2; ++kk) {
      const int c = (lk8 + kk * 32) * 2;
      const int ra = wm * 64 + m * 16 + lrow;
      offA[m][kk] = (ra * 128 + c) ^ ((ra & 7) << 4);
      const int rb = wn * 64 + m * 16 + lrow;
      offB[m][kk] = 32768 + ((rb * 128 + c) ^ ((rb & 7) << 4));
    }

  f32x4 acc[4][4] = {};

  // prologue: stage tiles 0,1 -> bufs 0,1; publish tile 0
#pragma unroll
  for (int j = 0; j < 6; ++j) stage(0, j, lds);
#pragma unroll
  for (int j = 0; j < 6; ++j) stage(1, j, lds + 49152);
  asm volatile("s_waitcnt vmcnt(6)" ::: "memory");
  __builtin_amdgcn_s_barrier();

  for (int tt = 0; tt < 32; ++tt) {
    char* cur = lds + (tt % 3) * 49152;
    char* nxt = lds + ((tt + 2) % 3) * 49152;
    const bool st = (tt + 2) < 32;

    // ---- phase 0: B all + A m{0,1}; stage chunks 0-2; MFMA m{0,1} ----
    bf16x8 bfr[4][2], afr[2][2];
#pragma unroll
    for (int n = 0; n < 4; ++n)
#pragma unroll
      for (int kk = 0; kk < 2; ++kk) bfr[n][kk] = *(const bf16x8*)(cur + offB[n][kk]);
#pragma unroll
    for (int m = 0; m < 2; ++m)
#pragma unroll
      for (int kk = 0; kk < 2; ++kk) afr[m][kk] = *(const bf16x8*)(cur + offA[m][kk]);
    if (st) { stage(tt + 2, 0, nxt); stage(tt + 2, 1, nxt); stage(tt + 2, 2, nxt); }
    __builtin_amdgcn_s_barrier();
    asm volatile("s_waitcnt lgkmcnt(0)" ::: "memory");
    __builtin_amdgcn_sched_barrier(0);
    __builtin_amdgcn_s_setprio(1);
#pragma unroll
    for (int m = 0; m < 2; ++m)
#pragma unroll
      for (int n = 0; n < 4; ++n)
#pragma unroll
        for (int kk = 0; kk < 2; ++kk)
          acc[m][n] = __builtin_amdgcn_mfma_f32_16x16x32_bf16(afr[m][kk], bfr[n][kk], acc[m][n], 0, 0, 0);
    __builtin_amdgcn_s_setprio(0);
    __builtin_amdgcn_s_barrier();

    // ---- phase 1: A m{2,3}; stage chunks 3-5; vmcnt; MFMA m{2,3} ----
#pragma unroll
    for (int m = 0; m < 2; ++m)
#pragma unroll
      for (int kk = 0; kk < 2; ++kk) afr[m][kk] = *(const bf16x8*)(cur + offA[m + 2][kk]);
    if (st) { stage(tt + 2, 3, nxt); stage(tt + 2, 4, nxt); stage(tt + 2, 5, nxt); }
    if (tt < 31) {
      if (st) asm volatile("s_waitcnt vmcnt(6)" ::: "memory");
      else    asm volatile("s_waitcnt vmcnt(0)" ::: "memory");
    }
    __builtin_amdgcn_s_barrier();
    asm volatile("s_waitcnt lgkmcnt(0)" ::: "memory");
    __builtin_amdgcn_sched_barrier(0);
    __builtin_amdgcn_s_setprio(1);
#pragma unroll
    for (int m = 0; m < 2; ++m)
#pragma unroll
      for (int n = 0; n < 4; ++n)
#pragma unroll
        for (int kk = 0; kk < 2; ++kk)
          acc[m + 2][n] = __builtin_amdgcn_mfma_f32_16x16x32_bf16(afr[m][kk], bfr[n][kk], acc[m + 2][n], 0, 0, 0);
    __builtin_amdgcn_s_setprio(0);
    __builtin_amdgcn_s_barrier();
  }

  // ---- epilogue ----
  const int g4 = g * 4;
#pragma unroll
  for (int mi = 0; mi < 4; ++mi) {
#pragma unroll
    for (int ni = 0; ni < 4; ++ni) {
      f32x4 v = acc[mi][ni];
      const int row0 = brow + wm * 64 + mi * 16 + g4;
      const int cols = bcol + wn * 64 + ni * 16 + lrow;   // col within slab / N
      if (slab == 3) {
        float* O = (float*)out0;
        const float bv = biasQ[cols];
#pragma unroll
        for (int r = 0; r < 4; ++r)
          O[(size_t)(row0 + r) * 2048 + cols] = v[r] + bv;
      } else if (slab == 2) {   // V -> Vt [B,H,HD,S], pi-permuted + swizzled
        u16* O = (u16*)out2;
        const float bv = biasV[cols];
        const int h = cols >> 7, d = cols & 127;
        const int bb = row0 >> 11, s = row0 & 2047;
        us4 ov;
#pragma unroll
        for (int r = 0; r < 4; ++r) ov[r] = f2bf(v[r] + bv);
        const int l = s & 63;
        const int kt = l >> 4, g2 = (l >> 2) & 3;
        const int c = ((kt >> 1) << 5) + (g2 << 3) + ((kt & 1) << 2);
        u16* base = O + ((size_t)(bb * 16 + h) * 128 + d) * 2048 + (s & ~63);
        *(us4*)((char*)base + ((unsigned)(c << 1) ^ (unsigned)((d & 7) << 4))) = ov;
      } else {                  // Q (0) / K (1): bias + RoPE
        u16* O = (u16*)(slab ? out1 : out0);
        const float bv = slab ? biasK[cols] : biasQ[cols];
        const int h = cols >> 7, d = cols & 127;
        const float sgn = (d & 1) ? 1.f : -1.f;
        const float QSCL = 0.08838834764831845f * 1.44269504088896340f;
#pragma unroll
        for (int r = 0; r < 4; ++r) {
          const int row = row0 + r, bb = row >> 11, s = row & 2047;
          float q = v[r] + bv;
          float p = __shfl_xor(q, 1);   // partner dim d^1 lives in lane^1
          float o = q * cosT[s * 128 + d] + sgn * p * sinT[s * 128 + d];
          u16* base = O + ((size_t)(bb * 16 + h) * 2048 + s) * 128;
          if (slab == 0) {
            base[d] = f2bf(o * QSCL);
          } else {
            *(u16*)((char*)base + (((unsigned)(d << 1)) ^ (unsigned)((s & 7) << 4))) = f2bf(o);
          }
        }
      }
    }
  }
}

// ---------------- causal flash attention ----------------
// Q: [BH][S][128] bf16 pre-scaled by 1/sqrt(128)*log2e, K: row-swizzled,
// Vt: [BH][128][S] pi-permuted + swizzled. AO out: [4096][2048] bf16.
__global__ __launch_bounds__(256, 2)
void attn_fwd(const u16* __restrict__ Q, const u16* __restrict__ K,
              const u16* __restrict__ Vt, u16* __restrict__ AO)
{
  __shared__ __align__(16) u16 Ks[2][64 * 128];
  __shared__ __align__(16) u16 Vs[2][128 * 64];
  const int t = threadIdx.x, w = t >> 6, lane = t & 63;
  const int lrow = lane & 15, g = lane >> 4, lk8 = g * 8;
  const int id = blockIdx.x;
  const int bh = (id & 7) | (((id >> 3) & 3) << 3);   // XCD-local bh grouping
  const int pr = id >> 5;                              // pair index 0..15
  const u16* Qg = Q + (size_t)bh * 2048 * 128;
  const u16* Kg = K + (size_t)bh * 2048 * 128;
  const u16* Vg = Vt + (size_t)bh * 128 * 2048;
  const int bb = bh >> 4, h = bh & 15;

  for (int half = 0; half < 2; ++half) {
    const int qt = half ? (31 - pr) : pr;
    const int q0 = qt * 64, qw = q0 + w * 16;
    const int nkv = qt + 1;
    const int qg = qw + lrow;   // this lane's q-row

    bf16x8 qf[4];
#pragma unroll
    for (int c = 0; c < 4; ++c)
      qf[c] = *(const bf16x8*)(Qg + (size_t)(qw + lrow) * 128 + lk8 + c * 32);

    f32x4 acc_o[8] = {};
    float m = -1e30f, lsum = 0.f;

    auto stage = [&](int i, int b) {
#pragma unroll
      for (int r = 0; r < 4; ++r) {
        int e = (r * 256 + t) * 8;
        async16(Kg + (size_t)i * 8192 + e, &Ks[b][r * 2048 + w * 512]);
        async16(Vg + (size_t)(e >> 6) * 2048 + i * 64 + (e & 63), &Vs[b][r * 2048 + w * 512]);
      }
    };

    stage(0, 0);
    for (int i = 0; i < nkv; ++i) {
      const int cur = i & 1;
      const bool pfch = (i + 1) < nkv;
      if (pfch) stage(i + 1, cur ^ 1);
      if (pfch) asm volatile("s_waitcnt vmcnt(8)" ::: "memory");
      else      asm volatile("s_waitcnt vmcnt(0)" ::: "memory");
      __builtin_amdgcn_s_barrier();
      __builtin_amdgcn_sched_barrier(0);

      // QK^T swapped: C col = q (lane&15), row = k
      f32x4 sc[4];
      __builtin_amdgcn_s_setprio(1);
#pragma unroll
      for (int kt = 0; kt < 4; ++kt) {
        f32x4 s = {};
        const int krow = kt * 16 + lrow;
        const char* kbase = (const char*)(&Ks[cur][krow * 128]);
        const unsigned sw = (unsigned)((krow & 7) << 4);
#pragma unroll
        for (int c = 0; c < 4; ++c) {
          bf16x8 kf = *(const bf16x8*)(kbase + ((unsigned)((lk8 + c * 32) << 1) ^ sw));
          s = __builtin_amdgcn_mfma_f32_16x16x32_bf16(kf, qf[c], s, 0, 0, 0);
        }
        sc[kt] = s;
      }
      __builtin_amdgcn_s_setprio(0);

      float p[4][4];
      const bool lastblk = (i == qt);
      if (lastblk) {
#pragma unroll
        for (int kt = 0; kt < 4; ++kt)
#pragma unroll
          for (int r = 0; r < 4; ++r) {
            int kg = i * 64 + kt * 16 + g * 4 + r;
            p[kt][r] = (kg > qg) ? -1e30f : sc[kt][r];
          }
      } else {
#pragma unroll
        for (int kt = 0; kt < 4; ++kt)
#pragma unroll
          for (int r = 0; r < 4; ++r) p[kt][r] = sc[kt][r];
      }

      float mm = p[0][0];
#pragma unroll
      for (int kt = 0; kt < 4; ++kt)
#pragma unroll
        for (int r = 0; r < 4; ++r) mm = fmaxf(mm, p[kt][r]);
      mm = fmaxf(mm, __shfl_xor(mm, 16));
      mm = fmaxf(mm, __shfl_xor(mm, 32));

      float rs = 0.f;
      if (__any(mm > m + 8.f)) {
        const float mn = fmaxf(m, mm);
        const float corr = exp2f(m - mn);
        m = mn;
#pragma unroll
        for (int kt = 0; kt < 4; ++kt)
#pragma unroll
          for (int r = 0; r < 4; ++r) { p[kt][r] = exp2f(p[kt][r] - m); rs += p[kt][r]; }
        rs += __shfl_xor(rs, 16);
        rs += __shfl_xor(rs, 32);
        lsum = lsum * corr + rs;
#pragma unroll
        for (int nt = 0; nt < 8; ++nt)
#pragma unroll
          for (int r = 0; r < 4; ++r) acc_o[nt][r] *= corr;
      } else {
#pragma unroll
        for (int kt = 0; kt < 4; ++kt)
#pragma unroll
          for (int r = 0; r < 4; ++r) { p[kt][r] = exp2f(p[kt][r] - m); rs += p[kt][r]; }
        rs += __shfl_xor(rs, 16);
        rs += __shfl_xor(rs, 32);
        lsum += rs;
      }

      bf16x8 pb[2];
#pragma unroll
      for (int kc = 0; kc < 2; ++kc) {
        union { u32 d[4]; bf16x8 v; } u;
        u.d[0] = pkbf(p[2 * kc][0], p[2 * kc][1]);
        u.d[1] = pkbf(p[2 * kc][2], p[2 * kc][3]);
        u.d[2] = pkbf(p[2 * kc + 1][0], p[2 * kc + 1][1]);
        u.d[3] = pkbf(p[2 * kc + 1][2], p[2 * kc + 1][3]);
        pb[kc] = u.v;
      }

      __builtin_amdgcn_s_setprio(1);
#pragma unroll
      for (int nt = 0; nt < 8; ++nt) {
        const int vrow = nt * 16 + lrow;
        const char* vbase = (const char*)(&Vs[cur][vrow * 64]);
        const unsigned sw2 = (unsigned)((vrow & 7) << 4);
#pragma unroll
        for (int kc = 0; kc < 2; ++kc) {
          bf16x8 vf = *(const bf16x8*)(vbase + ((unsigned)((lk8 + kc * 32) << 1) ^ sw2));
          acc_o[nt] = __builtin_amdgcn_mfma_f32_16x16x32_bf16(vf, pb[kc], acc_o[nt], 0, 0, 0);
        }
      }
      __builtin_amdgcn_s_setprio(0);
      __builtin_amdgcn_s_barrier();
    }

    const float inv_l = 1.f / lsum;
#pragma unroll
    for (int nt = 0; nt < 8; ++nt) {
      us4 ov;
#pragma unroll
      for (int r = 0; r < 4; ++r) ov[r] = f2bf(acc_o[nt][r] * inv_l);
      *(us4*)(AO + ((size_t)(bb * 2048 + qg)) * 2048 + h * 128 + nt * 16 + g * 4) = ov;
    }
  }
}

// ---------------- launch ----------------
extern "C" void kernel_launch(void* const* d_in, const int* in_sizes, int n_in,
                              void* d_out, int out_size, void* d_ws, size_t ws_size,
                              hipStream_t stream) {
  const float* x    = (const float*)d_in[0];
  const float* cosT = (const float*)d_in[1];
  const float* sinT = (const float*)d_in[2];
  const float* Wq   = (const float*)d_in[4];
  const float* bq   = (const float*)d_in[5];
  const float* Wk   = (const float*)d_in[6];
  const float* bk   = (const float*)d_in[7];
  const float* Wv   = (const float*)d_in[8];
  const float* bv   = (const float*)d_in[9];
  const float* Wo   = (const float*)d_in[10];
  const float* bo   = (const float*)d_in[11];
  float* out = (float*)d_out;

  char* ws = (char*)d_ws;
  u16* xb  = (u16*)(ws);                    // 16 MB  [4096][2048]
  u16* Wqb = (u16*)(ws + (16u << 20));      // 8 MB
  u16* Wkb = (u16*)(ws + (24u << 20));
  u16* Wvb = (u16*)(ws + (32u << 20));
  u16* Wob = (u16*)(ws + (40u << 20));
  u16* Qb  = (u16*)(ws + (48u << 20));      // 16 MB [BH][S][HD] (pre-scaled)
  u16* Kb  = (u16*)(ws + (64u << 20));      // 16 MB [BH][S][HD] swizzled
  u16* Vtb = (u16*)(ws + (80u << 20));      // 16 MB [BH][HD][S] permuted+swizzled
  u16* AOb = (u16*)(ws + (96u << 20));      // 16 MB [4096][2048]

  cast_bf16<<<8192, 256, 0, stream>>>(x,  xb,  4096 * 2048);
  cast_bf16<<<4096, 256, 0, stream>>>(Wq, Wqb, 2048 * 2048);
  cast_bf16<<<4096, 256, 0, stream>>>(Wk, Wkb, 2048 * 2048);
  cast_bf16<<<4096, 256, 0, stream>>>(Wv, Wvb, 2048 * 2048);
  cast_bf16<<<4096, 256, 0, stream>>>(Wo, Wob, 2048 * 2048);

  // fused QKV: N = 6144, grid = 16 m-tiles x 48 n-tiles = 768 (3 rounds/CU)
  gemm8p<<<768, 512, 0, stream>>>(xb, Wqb, Wkb, Wvb, bq, bk, bv, cosT, sinT,
                                  (void*)Qb, (void*)Kb, (void*)Vtb, 48, 1);

  attn_fwd<<<512, 256, 0, stream>>>(Qb, Kb, Vtb, AOb);

  // output proj: N = 2048, grid = 16 x 16 = 256 (1 block/CU)
  gemm8p<<<256, 512, 0, stream>>>(AOb, Wob, Wob, Wob, bo, bo, bo, nullptr, nullptr,
                                  (void*)out, nullptr, nullptr, 16, 0);
}